// Round 13
// baseline (5933.153 us; speedup 1.0000x reference)
//
#include <hip/hip_runtime.h>
#include <hip/hip_bf16.h>

#define QD 1024
#define AD 26
#define BD 128
#define LD 1024
#define NWG 128          // 32 q-slices x 4 batch-domains
#define FSTR 32          // uints per WG flag = 128 B line each
#define PSTR (8 * 32 * 64 * 8)   // ushorts per parity of packed alpha (256 KB)

typedef short bf16x8 __attribute__((ext_vector_type(8)));
typedef float f32x4 __attribute__((ext_vector_type(4)));

static __device__ __forceinline__ unsigned short f2bf(float f) {
    __hip_bfloat16 h = __float2bfloat16(f);
    return *reinterpret_cast<unsigned short*>(&h);
}

// Agent-scope relaxed 16B load (two 8B scoped loads; LLC-served when resident).
static __device__ __forceinline__ bf16x8 load_a16(const unsigned short* p) {
    unsigned long long lo = __hip_atomic_load((const unsigned long long*)p,
                                              __ATOMIC_RELAXED, __HIP_MEMORY_SCOPE_AGENT);
    unsigned long long hi = __hip_atomic_load((const unsigned long long*)(p + 4),
                                              __ATOMIC_RELAXED, __HIP_MEMORY_SCOPE_AGENT);
    union { unsigned long long q[2]; bf16x8 v; } u;
    u.q[0] = lo; u.q[1] = hi;
    return u.v;
}

// LLC-allocating 8B publish: atomic swap (result unused -> no-return
// global_atomic_swap_x2). RMW executes AT the LLC, so the line is allocated at the
// device coherence point -- consumers hit LLC instead of missing to HBM. (R11's
// plain scoped store wrote through without allocating: FETCH_SIZE showed every
// alpha line re-fetched from HBM each step.)
static __device__ __forceinline__ void store_a8(unsigned short* p, ushort4 v) {
    union { ushort4 s; unsigned long long q; } u; u.s = v;
    (void)__hip_atomic_exchange((unsigned long long*)p, u.q,
                                __ATOMIC_RELAXED, __HIP_MEMORY_SCOPE_AGENT);
}

// Row-softmax of trans_logits [1024,1024] -> bf16 packed as A-fragments of T^T.
// A-frag layout (16x16x32): A[m = lane&15][k = quad*8 + j].
__global__ void softmax_pack_T(const float* __restrict__ tl, unsigned short* __restrict__ tf) {
    const int i = blockIdx.x;      // q_in
    const int tid = threadIdx.x;   // 256
    __shared__ float red[256];
    float v[4];
    float m = -1e30f;
    for (int c = 0; c < 4; ++c) { v[c] = tl[i * QD + tid + 256 * c]; m = fmaxf(m, v[c]); }
    red[tid] = m; __syncthreads();
    for (int s = 128; s > 0; s >>= 1) { if (tid < s) red[tid] = fmaxf(red[tid], red[tid + s]); __syncthreads(); }
    m = red[0]; __syncthreads();
    float sum = 0.f;
    for (int c = 0; c < 4; ++c) { v[c] = expf(v[c] - m); sum += v[c]; }
    red[tid] = sum; __syncthreads();
    for (int s = 128; s > 0; s >>= 1) { if (tid < s) red[tid] += red[tid + s]; __syncthreads(); }
    const float inv = 1.0f / red[0];
    const int kt = i >> 5, quad = (i >> 3) & 3, j = i & 7;
    for (int c = 0; c < 4; ++c) {
        const int q = tid + 256 * c;
        const int mt = q >> 4, col = q & 15;
        tf[(size_t)((mt * 32 + kt) * 64 + quad * 16 + col) * 8 + j] = f2bf(v[c] * inv);
    }
}

// Row-softmax of emis_logits [1024,26] -> bf16 A-fragments (M=q, K=a padded to 32).
__global__ void softmax_pack_B(const float* __restrict__ el, unsigned short* __restrict__ bmf) {
    const int q = blockIdx.x * blockDim.x + threadIdx.x;
    if (q >= QD) return;
    float v[AD];
    float m = -1e30f;
    for (int a = 0; a < AD; ++a) { v[a] = el[q * AD + a]; m = fmaxf(m, v[a]); }
    float sum = 0.f;
    for (int a = 0; a < AD; ++a) { v[a] = expf(v[a] - m); sum += v[a]; }
    const float inv = 1.0f / sum;
    const int mt = q >> 4, col = q & 15;
    for (int a = 0; a < 32; ++a) {
        const float val = (a < AD) ? v[a] * inv : 0.f;
        bmf[(size_t)(mt * 64 + (a >> 3) * 16 + col) * 8 + (a & 7)] = f2bf(val);
    }
}

__global__ void softmax_pi(const float* __restrict__ il, float* __restrict__ pi) {
    const int tid = threadIdx.x;   // 1024
    __shared__ float red[1024];
    const float v = il[tid];
    red[tid] = v; __syncthreads();
    for (int s = 512; s > 0; s >>= 1) { if (tid < s) red[tid] = fmaxf(red[tid], red[tid + s]); __syncthreads(); }
    const float m = red[0]; __syncthreads();
    const float e = expf(v - m);
    red[tid] = e; __syncthreads();
    for (int s = 512; s > 0; s >>= 1) { if (tid < s) red[tid] += red[tid + s]; __syncthreads(); }
    pi[tid] = e / red[0];
}

// Cooperative scan, 128 WGs x 256 threads = 32 q-slices x 4 independent batch domains.
// Structure identical to R11 (proven correct) except the two publishes are
// LLC-allocating atomic swaps instead of write-through stores.
// Per step: each wave swaps its 8B fragment-packed alpha tile into apack ->
// vmcnt(0) drain (LLC ack) -> __syncthreads() -> tid0 swaps flags[bg][qs] = t+1 ->
// consumers poll 32 flag lines coalesced + ballot -> software-pipelined consume
// (all 64 coalesced 8B loads in flight, then 64 MFMAs). Overwrite safety: WG flag
// at t+1 implies all its waves' t+1 swaps acked, each of which data-depends on
// having finished reading alpha(t).
__launch_bounds__(256, 1)
__global__ void hmm_scan(const float* __restrict__ inputs,
                         const unsigned short* __restrict__ tf,
                         const unsigned short* __restrict__ bmf,
                         const float* __restrict__ pi,
                         unsigned short* __restrict__ apack,  // 2 x PSTR ushorts
                         unsigned int* __restrict__ flags,    // [4][32][FSTR] uint, zeroed
                         float* __restrict__ out) {
    const int tid   = threadIdx.x;
    const int wave  = tid >> 6;
    const int lane  = tid & 63;
    const int quad  = lane >> 4;
    const int col   = lane & 15;
    const int mtl   = wave & 1;
    const int bhalf = wave >> 1;
    const int qs    = (int)blockIdx.x >> 2;
    const int bg    = (int)blockIdx.x & 3;
    const int b     = bg * 32 + bhalf * 16 + col;   // this lane's batch
    const int qrow  = qs * 32 + mtl * 16 + quad * 4;
    const int grp   = bg * 2 + bhalf;               // packed group

    unsigned int* dom = flags + (size_t)bg * 32 * FSTR;
    unsigned int* myflag = dom + (size_t)qs * FSTR;
    const unsigned int* pollp = dom + (size_t)(lane & 31) * FSTR;

    // Producer store target (ushort offset within a parity).
    const int lane_c = (mtl * 2 + (quad >> 1)) * 16 + col;
    const size_t poff = (size_t)((grp * 32 + qs) * 64 + lane_c) * 8 + (quad & 1) * 4;
    // Consumer chunk base (ushort offset within a parity); chunk kt at +kt*512.
    const size_t coff = (size_t)(grp * 32) * 512 + (size_t)lane * 8;

    // All 32 T^T A-frags into registers (AGPR side of the unified file).
    bf16x8 tfr[32];
    {
        const bf16x8* tsrc = (const bf16x8*)tf + (size_t)(qs * 2 + mtl) * 32 * 64 + lane;
        #pragma unroll
        for (int kt = 0; kt < 32; ++kt) tfr[kt] = tsrc[(size_t)kt * 64];
    }
    const bf16x8 bmA = *(const bf16x8*)&bmf[(size_t)((qs * 2 + mtl) * 64 + lane) * 8];
    float pr[4];
    #pragma unroll
    for (int r = 0; r < 4; ++r) pr[r] = pi[qrow + r];

    bf16x8 ones;
    #pragma unroll
    for (int i = 0; i < 8; ++i) ones[i] = (short)0x3F80;

    const f32x4 fz = {0.f, 0.f, 0.f, 0.f};
    float ll = 0.f;

    // Emission(0): direct register loads.
    f32x4 e;
    {
        bf16x8 xb;
        #pragma unroll
        for (int j = 0; j < 8; ++j) {
            const int a = quad * 8 + j;
            const float v = (a < AD) ? inputs[(size_t)b * LD * AD + a] : 0.f;
            xb[j] = (short)f2bf(v);
        }
        e = __builtin_amdgcn_mfma_f32_16x16x32_bf16(bmA, xb, fz, 0, 0, 0);
    }

    f32x4 acc = fz, on = fz;

    for (int t = 0; t < LD; ++t) {
        // Hoist next step's emission input loads: they complete during the drain.
        float va[8];
        if (t + 1 < LD) {
            #pragma unroll
            for (int j = 0; j < 8; ++j) {
                const int a = quad * 8 + j;
                va[j] = (a < AD) ? inputs[((size_t)b * LD + (t + 1)) * AD + a] : 0.f;
            }
        }

        float v0[4];
        if (t == 0) {
            #pragma unroll
            for (int r = 0; r < 4; ++r) v0[r] = pr[r] * e[r];
        } else {
            const float i0 = 1.f / on[0];
            #pragma unroll
            for (int r = 0; r < 4; ++r) v0[r] = acc[r] * e[r] * i0;
        }
        ushort4 s0;
        s0.x = f2bf(v0[0]); s0.y = f2bf(v0[1]); s0.z = f2bf(v0[2]); s0.w = f2bf(v0[3]);
        store_a8(apack + (size_t)(t & 1) * PSTR + poff, s0);

        asm volatile("s_waitcnt vmcnt(0)" ::: "memory");   // swap acked at LLC (+input loads)
        __syncthreads();                                   // all 4 waves drained
        if (tid == 0)
            (void)__hip_atomic_exchange(myflag, (unsigned)(t + 1),
                                        __ATOMIC_RELAXED, __HIP_MEMORY_SCOPE_AGENT);
        if (qs == 0 && t > 0) ll += logf(on[0]);   // on[0] == c_{t-1}[lane's batch]

        if (t + 1 < LD) {
            // Emission(t+1) from the pre-loaded inputs while peers publish.
            bf16x8 xb;
            #pragma unroll
            for (int j = 0; j < 8; ++j) xb[j] = (short)f2bf(va[j]);
            e = __builtin_amdgcn_mfma_f32_16x16x32_bf16(bmA, xb, fz, 0, 0, 0);

            // WG-flag barrier: one coalesced load of the domain's 32 flag lines.
            {
                const unsigned target = (unsigned)(t + 1);
                for (;;) {
                    unsigned v = __hip_atomic_load(pollp, __ATOMIC_RELAXED,
                                                   __HIP_MEMORY_SCOPE_AGENT);
                    if (__ballot(v >= target) == ~0ULL) break;
                    __builtin_amdgcn_s_sleep(1);
                }
            }

            // Consume alpha(t), software-pipelined: pre-issue ALL 64 coalesced loads
            // into a 128-VGPR buffer, then drain with 64 MFMAs (fine-grained vmcnt).
            const unsigned short* cp = apack + (size_t)(t & 1) * PSTR + coff;
            bf16x8 bufr[32];
            #pragma unroll
            for (int kt = 0; kt < 32; ++kt)
                bufr[kt] = load_a16(cp + (size_t)kt * 512);
            acc = fz; on = fz;
            #pragma unroll
            for (int kt = 0; kt < 32; ++kt) {
                acc = __builtin_amdgcn_mfma_f32_16x16x32_bf16(tfr[kt], bufr[kt], acc, 0, 0, 0);
                on  = __builtin_amdgcn_mfma_f32_16x16x32_bf16(ones, bufr[kt], on, 0, 0, 0);
            }
        }
    }

    // Final normalizer c_{L-1}; only qs==0 waves produce output.
    if (qs == 0) {
        for (;;) {
            unsigned v = __hip_atomic_load(pollp, __ATOMIC_RELAXED,
                                           __HIP_MEMORY_SCOPE_AGENT);
            if (__ballot(v >= (unsigned)LD) == ~0ULL) break;
            __builtin_amdgcn_s_sleep(1);
        }
        const unsigned short* cp = apack + (size_t)((LD - 1) & 1) * PSTR + coff;
        bf16x8 bufr[32];
        #pragma unroll
        for (int kt = 0; kt < 32; ++kt)
            bufr[kt] = load_a16(cp + (size_t)kt * 512);
        f32x4 f0 = fz;
        #pragma unroll
        for (int kt = 0; kt < 32; ++kt)
            f0 = __builtin_amdgcn_mfma_f32_16x16x32_bf16(ones, bufr[kt], f0, 0, 0, 0);
        if (mtl == 0 && quad == 0) out[b] = ll + logf(f0[0]);
    }
}

extern "C" void kernel_launch(void* const* d_in, const int* in_sizes, int n_in,
                              void* d_out, int out_size, void* d_ws, size_t ws_size,
                              hipStream_t stream) {
    const float* inputs       = (const float*)d_in[0];
    const float* init_logits  = (const float*)d_in[1];
    const float* trans_logits = (const float*)d_in[2];
    const float* emis_logits  = (const float*)d_in[3];
    float* out = (float*)d_out;

    unsigned short* tf    = (unsigned short*)d_ws;                 // 2 MB
    unsigned short* bmf   = tf + (size_t)QD * QD;                  // 64 KB
    float* pi             = (float*)(bmf + (size_t)QD * 32);       // 4 KB
    unsigned short* apack = (unsigned short*)(pi + QD);            // 512 KB
    unsigned int* flagsb  = (unsigned int*)(apack + (size_t)2 * PSTR);  // 16 KB

    hipMemsetAsync(flagsb, 0, (size_t)4 * 32 * FSTR * sizeof(unsigned int), stream);

    softmax_pack_T<<<1024, 256, 0, stream>>>(trans_logits, tf);
    softmax_pack_B<<<4, 256, 0, stream>>>(emis_logits, bmf);
    softmax_pi<<<1, 1024, 0, stream>>>(init_logits, pi);

    void* args[] = {(void*)&inputs, (void*)&tf, (void*)&bmf, (void*)&pi,
                    (void*)&apack, (void*)&flagsb, (void*)&out};
    hipLaunchCooperativeKernel((const void*)hmm_scan, dim3(NWG), dim3(256),
                               args, 0, stream);
}

// Round 15
// 3956.853 us; speedup vs baseline: 1.4995x; 1.4995x over previous
//
#include <hip/hip_runtime.h>
#include <hip/hip_bf16.h>

#define QD 1024
#define AD 26
#define BD 128
#define LD 1024
#define NWG 128          // 32 q-slices x 4 batch-domains
#define PSTR (8 * 32 * 64 * 8)   // ushorts per parity of packed alpha (256 KB)

typedef short bf16x8 __attribute__((ext_vector_type(8)));
typedef float f32x4 __attribute__((ext_vector_type(4)));

static __device__ __forceinline__ unsigned short f2bf(float f) {
    __hip_bfloat16 h = __float2bfloat16(f);
    return *reinterpret_cast<unsigned short*>(&h);
}

// Agent-scope relaxed 16B load (two 8B atomic loads -> served at device coherence pt).
static __device__ __forceinline__ bf16x8 load_a16(const unsigned short* p) {
    unsigned long long lo = __hip_atomic_load((const unsigned long long*)p,
                                              __ATOMIC_RELAXED, __HIP_MEMORY_SCOPE_AGENT);
    unsigned long long hi = __hip_atomic_load((const unsigned long long*)(p + 4),
                                              __ATOMIC_RELAXED, __HIP_MEMORY_SCOPE_AGENT);
    union { unsigned long long q[2]; bf16x8 v; } u;
    u.q[0] = lo; u.q[1] = hi;
    return u.v;
}

// Agent-scope relaxed 8B store (fire-and-forget; atomic => no tearing of a granule).
static __device__ __forceinline__ void store_a8(unsigned short* p, ushort4 v) {
    union { ushort4 s; unsigned long long q; } u; u.s = v;
    __hip_atomic_store((unsigned long long*)p, u.q,
                       __ATOMIC_RELAXED, __HIP_MEMORY_SCOPE_AGENT);
}

// Row-softmax of trans_logits [1024,1024] -> bf16 packed as A-fragments of T^T.
// A-frag layout (16x16x32): A[m = lane&15][k = quad*8 + j].
__global__ void softmax_pack_T(const float* __restrict__ tl, unsigned short* __restrict__ tf) {
    const int i = blockIdx.x;      // q_in
    const int tid = threadIdx.x;   // 256
    __shared__ float red[256];
    float v[4];
    float m = -1e30f;
    for (int c = 0; c < 4; ++c) { v[c] = tl[i * QD + tid + 256 * c]; m = fmaxf(m, v[c]); }
    red[tid] = m; __syncthreads();
    for (int s = 128; s > 0; s >>= 1) { if (tid < s) red[tid] = fmaxf(red[tid], red[tid + s]); __syncthreads(); }
    m = red[0]; __syncthreads();
    float sum = 0.f;
    for (int c = 0; c < 4; ++c) { v[c] = expf(v[c] - m); sum += v[c]; }
    red[tid] = sum; __syncthreads();
    for (int s = 128; s > 0; s >>= 1) { if (tid < s) red[tid] += red[tid + s]; __syncthreads(); }
    const float inv = 1.0f / red[0];
    const int kt = i >> 5, quad = (i >> 3) & 3, j = i & 7;
    for (int c = 0; c < 4; ++c) {
        const int q = tid + 256 * c;
        const int mt = q >> 4, col = q & 15;
        tf[(size_t)((mt * 32 + kt) * 64 + quad * 16 + col) * 8 + j] = f2bf(v[c] * inv);
    }
}

// Row-softmax of emis_logits [1024,26] -> bf16 A-fragments (M=q, K=a padded to 32).
__global__ void softmax_pack_B(const float* __restrict__ el, unsigned short* __restrict__ bmf) {
    const int q = blockIdx.x * blockDim.x + threadIdx.x;
    if (q >= QD) return;
    float v[AD];
    float m = -1e30f;
    for (int a = 0; a < AD; ++a) { v[a] = el[q * AD + a]; m = fmaxf(m, v[a]); }
    float sum = 0.f;
    for (int a = 0; a < AD; ++a) { v[a] = expf(v[a] - m); sum += v[a]; }
    const float inv = 1.0f / sum;
    const int mt = q >> 4, col = q & 15;
    for (int a = 0; a < 32; ++a) {
        const float val = (a < AD) ? v[a] * inv : 0.f;
        bmf[(size_t)(mt * 64 + (a >> 3) * 16 + col) * 8 + (a & 7)] = f2bf(val);
    }
}

__global__ void softmax_pi(const float* __restrict__ il, float* __restrict__ pi) {
    const int tid = threadIdx.x;   // 1024
    __shared__ float red[1024];
    const float v = il[tid];
    red[tid] = v; __syncthreads();
    for (int s = 512; s > 0; s >>= 1) { if (tid < s) red[tid] = fmaxf(red[tid], red[tid + s]); __syncthreads(); }
    const float m = red[0]; __syncthreads();
    const float e = expf(v - m);
    red[tid] = e; __syncthreads();
    for (int s = 512; s > 0; s >>= 1) { if (tid < s) red[tid] += red[tid + s]; __syncthreads(); }
    pi[tid] = e / red[0];
}

// Scan: 128 WGs x 256 threads = 32 q-slices x 4 independent batch domains. PLAIN
// launch (128 blocks on 256 CUs are co-resident by dispatch; the cooperative API
// is not needed and its silent launch-rejection was the suspected R9/R10/R12/R14
// failure mode). 512 independent waves; zero LDS; NO FLAGS, NO POLLS, NO DRAINS.
// Self-validating exchange: alpha >= 0, so bf16 sign bits are free tag bits.
// Producer tags elements 2,3 of each 8-B granule with phase=(t>>1)&1. Consumer
// speculatively loads chunks (the sweep IS the poll), checks sign patterns,
// retries while stale, strips signs, MFMAs. A slot only ever holds t, t-2
// (opposite phase), or 0xAA fill (signs 1111, invalid for both phases; apack is
// memset in kernel_launch). Anti-overrun: the t+1 store happens only after fully
// validating all of t, which implies every reader of the t-1 slot has finished.
// Consume runs in two 16-chunk halves to keep live registers below the proven
// R8 envelope (only bufr[16] is live across a retry back-edge).
__launch_bounds__(256, 1)
__global__ void hmm_scan(const float* __restrict__ inputs,
                         const unsigned short* __restrict__ tf,
                         const unsigned short* __restrict__ bmf,
                         const float* __restrict__ pi,
                         unsigned short* __restrict__ apack,  // 2 x PSTR ushorts (0xAA)
                         float* __restrict__ out) {
    const int tid   = threadIdx.x;
    const int wave  = tid >> 6;
    const int lane  = tid & 63;
    const int quad  = lane >> 4;
    const int col   = lane & 15;
    const int mtl   = wave & 1;
    const int bhalf = wave >> 1;
    const int qs    = (int)blockIdx.x >> 2;
    const int bg    = (int)blockIdx.x & 3;
    const int b     = bg * 32 + bhalf * 16 + col;   // this lane's batch
    const int qrow  = qs * 32 + mtl * 16 + quad * 4;
    const int grp   = bg * 2 + bhalf;               // packed group

    // Producer store target (ushort offset within a parity).
    const int lane_c = (mtl * 2 + (quad >> 1)) * 16 + col;
    const size_t poff = (size_t)((grp * 32 + qs) * 64 + lane_c) * 8 + (quad & 1) * 4;
    // Consumer chunk base (ushort offset within a parity); chunk kt at +kt*512.
    const size_t coff = (size_t)(grp * 32) * 512 + (size_t)lane * 8;

    // All 32 T^T A-frags into registers (AGPR side of the unified file).
    bf16x8 tfr[32];
    {
        const bf16x8* tsrc = (const bf16x8*)tf + (size_t)(qs * 2 + mtl) * 32 * 64 + lane;
        #pragma unroll
        for (int kt = 0; kt < 32; ++kt) tfr[kt] = tsrc[(size_t)kt * 64];
    }
    const bf16x8 bmA = *(const bf16x8*)&bmf[(size_t)((qs * 2 + mtl) * 64 + lane) * 8];
    float pr[4];
    #pragma unroll
    for (int r = 0; r < 4; ++r) pr[r] = pi[qrow + r];

    bf16x8 ones;
    #pragma unroll
    for (int i = 0; i < 8; ++i) ones[i] = (short)0x3F80;

    const f32x4 fz = {0.f, 0.f, 0.f, 0.f};
    const unsigned M = 0x80008000u;
    float ll = 0.f;

    // Emission(0): direct register loads.
    f32x4 e;
    {
        bf16x8 xb;
        #pragma unroll
        for (int j = 0; j < 8; ++j) {
            const int a = quad * 8 + j;
            const float v = (a < AD) ? inputs[(size_t)b * LD * AD + a] : 0.f;
            xb[j] = (short)f2bf(v);
        }
        e = __builtin_amdgcn_mfma_f32_16x16x32_bf16(bmA, xb, fz, 0, 0, 0);
    }

    f32x4 acc = fz, on = fz;

    for (int t = 0; t < LD; ++t) {
        float v0[4];
        if (t == 0) {
            #pragma unroll
            for (int r = 0; r < 4; ++r) v0[r] = pr[r] * e[r];
        } else {
            const float i0 = 1.f / on[0];
            #pragma unroll
            for (int r = 0; r < 4; ++r) v0[r] = acc[r] * e[r] * i0;
        }
        // Tag elements 2,3 with phase(t); fire-and-forget atomic store.
        const unsigned short tagbit = (unsigned short)(((t >> 1) & 1) << 15);
        ushort4 s0;
        s0.x = f2bf(v0[0]); s0.y = f2bf(v0[1]);
        s0.z = (unsigned short)(f2bf(v0[2]) | tagbit);
        s0.w = (unsigned short)(f2bf(v0[3]) | tagbit);
        store_a8(apack + (size_t)(t & 1) * PSTR + poff, s0);

        if (qs == 0 && t > 0) ll += logf(on[0]);   // on[0] == c_{t-1}[lane's batch]

        if (t + 1 < LD) {
            // Emission(t+1) while our store is in flight.
            bf16x8 xb;
            #pragma unroll
            for (int j = 0; j < 8; ++j) {
                const int a = quad * 8 + j;
                const float v = (a < AD)
                    ? inputs[((size_t)b * LD + (t + 1)) * AD + a] : 0.f;
                xb[j] = (short)f2bf(v);
            }
            e = __builtin_amdgcn_mfma_f32_16x16x32_bf16(bmA, xb, fz, 0, 0, 0);

            // Validating consume of alpha(t), two halves of 16 chunks each.
            const unsigned short* cp = apack + (size_t)(t & 1) * PSTR + coff;
            const unsigned E = ((t >> 1) & 1) ? M : 0u;
            acc = fz; on = fz;
            #pragma unroll
            for (int h = 0; h < 2; ++h) {
                bf16x8 bufr[16];
                unsigned bad;
                do {
                    #pragma unroll
                    for (int k = 0; k < 16; ++k)
                        bufr[k] = load_a16(cp + (size_t)(h * 16 + k) * 512);
                    bad = 0u;
                    #pragma unroll
                    for (int k = 0; k < 16; ++k) {
                        union { bf16x8 v; uint4 u; } w; w.v = bufr[k];
                        bad |= (w.u.x | w.u.z | (w.u.y ^ E) | (w.u.w ^ E)) & M;
                    }
                } while (__ballot(bad == 0u) != ~0ULL);
                #pragma unroll
                for (int k = 0; k < 16; ++k) {
                    union { bf16x8 v; uint4 u; } w; w.v = bufr[k];
                    w.u.x &= ~M; w.u.y &= ~M; w.u.z &= ~M; w.u.w &= ~M;
                    acc = __builtin_amdgcn_mfma_f32_16x16x32_bf16(tfr[h * 16 + k], w.v, acc, 0, 0, 0);
                    on  = __builtin_amdgcn_mfma_f32_16x16x32_bf16(ones, w.v, on, 0, 0, 0);
                }
            }
        }
    }

    // Final normalizer c_{L-1}; only qs==0 waves produce output.
    if (qs == 0) {
        const unsigned short* cp = apack + (size_t)((LD - 1) & 1) * PSTR + coff;
        const unsigned E = (((LD - 1) >> 1) & 1) ? M : 0u;
        f32x4 f0 = fz;
        #pragma unroll
        for (int h = 0; h < 2; ++h) {
            bf16x8 bufr[16];
            unsigned bad;
            do {
                #pragma unroll
                for (int k = 0; k < 16; ++k)
                    bufr[k] = load_a16(cp + (size_t)(h * 16 + k) * 512);
                bad = 0u;
                #pragma unroll
                for (int k = 0; k < 16; ++k) {
                    union { bf16x8 v; uint4 u; } w; w.v = bufr[k];
                    bad |= (w.u.x | w.u.z | (w.u.y ^ E) | (w.u.w ^ E)) & M;
                }
            } while (__ballot(bad == 0u) != ~0ULL);
            #pragma unroll
            for (int k = 0; k < 16; ++k) {
                union { bf16x8 v; uint4 u; } w; w.v = bufr[k];
                w.u.x &= ~M; w.u.y &= ~M; w.u.z &= ~M; w.u.w &= ~M;
                f0 = __builtin_amdgcn_mfma_f32_16x16x32_bf16(ones, w.v, f0, 0, 0, 0);
            }
        }
        if (mtl == 0 && quad == 0) out[b] = ll + logf(f0[0]);
    }
}

extern "C" void kernel_launch(void* const* d_in, const int* in_sizes, int n_in,
                              void* d_out, int out_size, void* d_ws, size_t ws_size,
                              hipStream_t stream) {
    const float* inputs       = (const float*)d_in[0];
    const float* init_logits  = (const float*)d_in[1];
    const float* trans_logits = (const float*)d_in[2];
    const float* emis_logits  = (const float*)d_in[3];
    float* out = (float*)d_out;

    unsigned short* tf    = (unsigned short*)d_ws;                 // 2 MB
    unsigned short* bmf   = tf + (size_t)QD * QD;                  // 64 KB
    float* pi             = (float*)(bmf + (size_t)QD * 32);       // 4 KB
    unsigned short* apack = (unsigned short*)(pi + QD);            // 512 KB

    // Self-contained tag init: 0xAA bytes => every bf16 sign bit set => invalid
    // for BOTH phases (phase 0 expects sign 0 everywhere; phase 1 expects sign 0
    // on the untagged elements).
    hipMemsetAsync(apack, 0xAA, (size_t)2 * PSTR * sizeof(unsigned short), stream);

    softmax_pack_T<<<1024, 256, 0, stream>>>(trans_logits, tf);
    softmax_pack_B<<<4, 256, 0, stream>>>(emis_logits, bmf);
    softmax_pi<<<1, 1024, 0, stream>>>(init_logits, pi);

    // Plain launch: 128 blocks co-resident on 256 CUs by dispatch; no cooperative
    // API (its unchecked failure was the suspected zero-output mode in R9-R14).
    hmm_scan<<<NWG, 256, 0, stream>>>(inputs, tf, bmf, pi, apack, out);
}